// Round 1
// baseline (565.028 us; speedup 1.0000x reference)
//
#include <hip/hip_runtime.h>
#include <cmath>

namespace {
constexpr int Cc = 256, CKc = 32, CVc = 32, KKc = 9;
constexpr int Bc = 8, Hc = 128, Wc = 128, HWc = Hc * Wc;
}

// ---------------- Kernel 1: k1 = relu(W_k1 x + b), v = W_v x + b ----------------
__global__ __launch_bounds__(256) void ns_k1v(
    const float* __restrict__ x,
    const float* __restrict__ k1_w, const float* __restrict__ k1_b,
    const float* __restrict__ v_w,  const float* __restrict__ v_b,
    float* __restrict__ k1, float* __restrict__ v)
{
    const int gid = blockIdx.x * 256 + threadIdx.x;   // one thread per pixel
    const int b = gid / HWc;
    const int p = gid - b * HWc;
    const float* xb = x + (size_t)b * Cc * HWc + p;

    float acck[CKc], accv[CVc];
#pragma unroll
    for (int k = 0; k < CKc; ++k) { acck[k] = 0.f; accv[k] = 0.f; }

    for (int c0 = 0; c0 < Cc; c0 += 8) {
        float xv[8];
#pragma unroll
        for (int i = 0; i < 8; ++i) xv[i] = xb[(size_t)(c0 + i) * HWc];
#pragma unroll
        for (int k = 0; k < CKc; ++k) {
#pragma unroll
            for (int i = 0; i < 8; ++i) {
                acck[k] = fmaf(k1_w[k * Cc + c0 + i], xv[i], acck[k]);
                accv[k] = fmaf(v_w [k * Cc + c0 + i], xv[i], accv[k]);
            }
        }
    }

    float* k1p = k1 + (size_t)b * CKc * HWc + p;
    float* vp  = v  + (size_t)b * CVc * HWc + p;
#pragma unroll
    for (int k = 0; k < CKc; ++k) {
        float kv = acck[k] + k1_b[k];
        k1p[(size_t)k * HWc] = kv > 0.f ? kv : 0.f;
        vp [(size_t)k * HWc] = accv[k] + v_b[k];
    }
}

// ------- Kernel 2: depthwise 3x3 on k1 (+bias), 1x1 CK->9 (+bias), softmax -------
__global__ __launch_bounds__(256) void ns_wts(
    const float* __restrict__ k1,
    const float* __restrict__ dw_w, const float* __restrict__ dw_b,
    const float* __restrict__ k3_w, const float* __restrict__ k3_b,
    float* __restrict__ wts)
{
    const int gid = blockIdx.x * 256 + threadIdx.x;
    const int b = gid / HWc;
    const int p = gid - b * HWc;
    const int h = p / Wc;
    const int w = p - h * Wc;
    const float* k1b = k1 + (size_t)b * CKc * HWc;

    float t[CKc];
#pragma unroll
    for (int ck = 0; ck < CKc; ++ck) t[ck] = dw_b[ck];

#pragma unroll
    for (int i = 0; i < 3; ++i) {
        const int hh = h + i - 1;
        if (hh < 0 || hh >= Hc) continue;
#pragma unroll
        for (int j = 0; j < 3; ++j) {
            const int ww = w + j - 1;
            if (ww < 0 || ww >= Wc) continue;
            const int off = hh * Wc + ww;
#pragma unroll
            for (int ck = 0; ck < CKc; ++ck)
                t[ck] = fmaf(k1b[(size_t)ck * HWc + off], dw_w[ck * KKc + i * 3 + j], t[ck]);
        }
    }

    float logit[KKc];
#pragma unroll
    for (int kk = 0; kk < KKc; ++kk) logit[kk] = k3_b[kk];
#pragma unroll
    for (int ck = 0; ck < CKc; ++ck) {
#pragma unroll
        for (int kk = 0; kk < KKc; ++kk)
            logit[kk] = fmaf(k3_w[kk * CKc + ck], t[ck], logit[kk]);
    }

    float m = logit[0];
#pragma unroll
    for (int kk = 1; kk < KKc; ++kk) m = fmaxf(m, logit[kk]);
    float s = 0.f;
#pragma unroll
    for (int kk = 0; kk < KKc; ++kk) { logit[kk] = expf(logit[kk] - m); s += logit[kk]; }
    const float inv = 1.f / s;

    float* wb = wts + (size_t)b * KKc * HWc + p;
#pragma unroll
    for (int kk = 0; kk < KKc; ++kk) wb[(size_t)kk * HWc] = logit[kk] * inv;
}

// --- Kernel 3: y = sum_kk wts*v(neighbor); out = x + W_o y + b_o (residual) ---
__global__ __launch_bounds__(256) void ns_out(
    const float* __restrict__ x,
    const float* __restrict__ v,
    const float* __restrict__ wts,
    const float* __restrict__ o_w, const float* __restrict__ o_b,
    float* __restrict__ out)
{
    const int gid = blockIdx.x * 256 + threadIdx.x;
    const int b = gid / HWc;
    const int p = gid - b * HWc;
    const int h = p / Wc;
    const int w = p - h * Wc;

    const float* wb = wts + (size_t)b * KKc * HWc + p;
    float wt[KKc];
#pragma unroll
    for (int kk = 0; kk < KKc; ++kk) wt[kk] = wb[(size_t)kk * HWc];

    float y[CVc];
#pragma unroll
    for (int cv = 0; cv < CVc; ++cv) y[cv] = 0.f;

    const float* vb = v + (size_t)b * CVc * HWc;
#pragma unroll
    for (int i = 0; i < 3; ++i) {
        const int hh = h + i - 1;
        if (hh < 0 || hh >= Hc) continue;
#pragma unroll
        for (int j = 0; j < 3; ++j) {
            const int ww = w + j - 1;
            if (ww < 0 || ww >= Wc) continue;
            const int off = hh * Wc + ww;
            const float wv = wt[i * 3 + j];
#pragma unroll
            for (int cv = 0; cv < CVc; ++cv)
                y[cv] = fmaf(wv, vb[(size_t)cv * HWc + off], y[cv]);
        }
    }

    const float* xb = x + (size_t)b * Cc * HWc + p;
    float* ob = out + (size_t)b * Cc * HWc + p;
#pragma unroll 4
    for (int o = 0; o < Cc; ++o) {
        float acc = o_b[o] + xb[(size_t)o * HWc];
#pragma unroll
        for (int cv = 0; cv < CVc; ++cv)
            acc = fmaf(o_w[o * CVc + cv], y[cv], acc);
        ob[(size_t)o * HWc] = acc;
    }
}

extern "C" void kernel_launch(void* const* d_in, const int* in_sizes, int n_in,
                              void* d_out, int out_size, void* d_ws, size_t ws_size,
                              hipStream_t stream)
{
    const float* x    = (const float*)d_in[0];
    const float* k1_w = (const float*)d_in[1];
    const float* k1_b = (const float*)d_in[2];
    const float* dw_w = (const float*)d_in[3];
    const float* dw_b = (const float*)d_in[4];
    const float* k3_w = (const float*)d_in[5];
    const float* k3_b = (const float*)d_in[6];
    const float* v_w  = (const float*)d_in[7];
    const float* v_b  = (const float*)d_in[8];
    const float* o_w  = (const float*)d_in[9];
    const float* o_b  = (const float*)d_in[10];
    float* out = (float*)d_out;

    // workspace: k1 (16 MiB) | v (16 MiB) | wts (4.5 MiB)
    float* k1  = (float*)d_ws;
    float* v   = k1 + (size_t)Bc * CKc * HWc;
    float* wts = v  + (size_t)Bc * CVc * HWc;

    const int nthreads = Bc * HWc;          // 131072 pixels
    dim3 grid(nthreads / 256), block(256);

    ns_k1v<<<grid, block, 0, stream>>>(x, k1_w, k1_b, v_w, v_b, k1, v);
    ns_wts<<<grid, block, 0, stream>>>(k1, dw_w, dw_b, k3_w, k3_b, wts);
    ns_out<<<grid, block, 0, stream>>>(x, v, wts, o_w, o_b, out);
}

// Round 2
// 505.942 us; speedup vs baseline: 1.1168x; 1.1168x over previous
//
#include <hip/hip_runtime.h>
#include <cmath>

namespace {
constexpr int Cc = 256, CKc = 32, CVc = 32, KKc = 9;
constexpr int Bc = 8, Hc = 128, Wc = 128, HWc = Hc * Wc;
constexpr int TPX = 64;   // pixels per block for k1v/out kernels
}

// ---- Kernel 1: k1 = relu(W_k1 x + b), v = W_v x + b (LDS-tiled, 4 og groups) ----
__global__ __launch_bounds__(256) void ns_k1v(
    const float* __restrict__ x,
    const float* __restrict__ k1_w, const float* __restrict__ k1_b,
    const float* __restrict__ v_w,  const float* __restrict__ v_b,
    float* __restrict__ k1, float* __restrict__ v)
{
    __shared__ float xs[64][TPX];               // 16 KiB: [channel chunk][pixel]
    const int flat0 = blockIdx.x * TPX;
    const int b = flat0 / HWc;
    const int pbase = flat0 - b * HWc;          // HW % TPX == 0, tile stays in batch
    const int tid = threadIdx.x;
    const int px = tid & 63;
    const int og = tid >> 6;                    // 0..3 : k[0:16],k[16:32],v[0:16],v[16:32]

    const float* xb = x + (size_t)b * Cc * HWc + pbase;

    const float* wbase;
    const float* bbase;
    float* obase;
    bool is_k = og < 2;
    if (is_k) {
        wbase = k1_w + og * 16 * Cc;
        bbase = k1_b + og * 16;
        obase = k1 + ((size_t)b * CKc + og * 16) * HWc + pbase;
    } else {
        wbase = v_w + (og - 2) * 16 * Cc;
        bbase = v_b + (og - 2) * 16;
        obase = v + ((size_t)b * CVc + (og - 2) * 16) * HWc + pbase;
    }

    float acc[16];
#pragma unroll
    for (int o = 0; o < 16; ++o) acc[o] = 0.f;

    for (int c0 = 0; c0 < Cc; c0 += 64) {
        // stage 64 channels x 64 px (coalesced float4 rows)
#pragma unroll
        for (int pass = 0; pass < 4; ++pass) {
            const int ch = (tid >> 4) + pass * 16;
            const int pq = (tid & 15) * 4;
            *(float4*)&xs[ch][pq] = *(const float4*)(xb + (size_t)(c0 + ch) * HWc + pq);
        }
        __syncthreads();
#pragma unroll 16
        for (int ch = 0; ch < 64; ++ch) {
            const float xv = xs[ch][px];
            const float* wc = wbase + (c0 + ch);
#pragma unroll
            for (int o = 0; o < 16; ++o)
                acc[o] = fmaf(wc[o * Cc], xv, acc[o]);
        }
        __syncthreads();
    }

#pragma unroll
    for (int o = 0; o < 16; ++o) {
        float r = acc[o] + bbase[o];
        if (is_k) r = fmaxf(r, 0.f);
        obase[(size_t)o * HWc + px] = r;
    }
}

// -- Kernel 2: depthwise 3x3 + 1x1 CK->9 + softmax + unfold-aggregate -> y[B,CV,H,W] --
__global__ __launch_bounds__(256) void ns_wts_y(
    const float* __restrict__ k1,
    const float* __restrict__ v,
    const float* __restrict__ dw_w, const float* __restrict__ dw_b,
    const float* __restrict__ k3_w, const float* __restrict__ k3_b,
    float* __restrict__ y)
{
    const int gid = blockIdx.x * 256 + threadIdx.x;
    const int b = gid / HWc;
    const int p = gid - b * HWc;
    const int h = p / Wc;
    const int w = p - h * Wc;
    const float* k1b = k1 + (size_t)b * CKc * HWc;

    float t[CKc];
#pragma unroll
    for (int ck = 0; ck < CKc; ++ck) t[ck] = dw_b[ck];

#pragma unroll
    for (int i = 0; i < 3; ++i) {
        const int hh = h + i - 1;
        if (hh < 0 || hh >= Hc) continue;
#pragma unroll
        for (int j = 0; j < 3; ++j) {
            const int ww = w + j - 1;
            if (ww < 0 || ww >= Wc) continue;
            const int off = hh * Wc + ww;
#pragma unroll
            for (int ck = 0; ck < CKc; ++ck)
                t[ck] = fmaf(k1b[(size_t)ck * HWc + off], dw_w[ck * KKc + i * 3 + j], t[ck]);
        }
    }

    float logit[KKc];
#pragma unroll
    for (int kk = 0; kk < KKc; ++kk) logit[kk] = k3_b[kk];
#pragma unroll
    for (int ck = 0; ck < CKc; ++ck) {
#pragma unroll
        for (int kk = 0; kk < KKc; ++kk)
            logit[kk] = fmaf(k3_w[kk * CKc + ck], t[ck], logit[kk]);
    }

    float m = logit[0];
#pragma unroll
    for (int kk = 1; kk < KKc; ++kk) m = fmaxf(m, logit[kk]);
    float s = 0.f;
#pragma unroll
    for (int kk = 0; kk < KKc; ++kk) { logit[kk] = expf(logit[kk] - m); s += logit[kk]; }
    const float inv = 1.f / s;
#pragma unroll
    for (int kk = 0; kk < KKc; ++kk) logit[kk] *= inv;

    // unfold-aggregate: yv[cv] = sum_kk wts[kk] * v[cv, neighbor kk]
    float yv[CVc];
#pragma unroll
    for (int cv = 0; cv < CVc; ++cv) yv[cv] = 0.f;

    const float* vb = v + (size_t)b * CVc * HWc;
#pragma unroll
    for (int i = 0; i < 3; ++i) {
        const int hh = h + i - 1;
        if (hh < 0 || hh >= Hc) continue;
#pragma unroll
        for (int j = 0; j < 3; ++j) {
            const int ww = w + j - 1;
            if (ww < 0 || ww >= Wc) continue;
            const int off = hh * Wc + ww;
            const float wv = logit[i * 3 + j];
#pragma unroll
            for (int cv = 0; cv < CVc; ++cv)
                yv[cv] = fmaf(wv, vb[(size_t)cv * HWc + off], yv[cv]);
        }
    }

    float* yb = y + (size_t)b * CVc * HWc + p;
#pragma unroll
    for (int cv = 0; cv < CVc; ++cv) yb[(size_t)cv * HWc] = yv[cv];
}

// ---- Kernel 3: out = x + W_o y + b_o (64 px/block, 4 output-channel groups) ----
__global__ __launch_bounds__(256) void ns_out(
    const float* __restrict__ x,
    const float* __restrict__ y,
    const float* __restrict__ o_w, const float* __restrict__ o_b,
    float* __restrict__ out)
{
    const int flat0 = blockIdx.x * TPX;
    const int b = flat0 / HWc;
    const int pbase = flat0 - b * HWc;
    const int tid = threadIdx.x;
    const int px = tid & 63;
    const int og = tid >> 6;                    // 64 output channels per group

    const float* yb = y + (size_t)b * CVc * HWc + pbase + px;
    float yv[CVc];
#pragma unroll
    for (int cv = 0; cv < CVc; ++cv) yv[cv] = yb[(size_t)cv * HWc];

    const float* xb = x + ((size_t)b * Cc + og * 64) * HWc + pbase + px;
    float* ob = out + ((size_t)b * Cc + og * 64) * HWc + pbase + px;
    const float* wrow = o_w + og * 64 * CVc;
    const float* brow = o_b + og * 64;

#pragma unroll 4
    for (int o = 0; o < 64; ++o) {
        float acc = brow[o] + xb[(size_t)o * HWc];
#pragma unroll
        for (int cv = 0; cv < CVc; ++cv)
            acc = fmaf(wrow[o * CVc + cv], yv[cv], acc);
        ob[(size_t)o * HWc] = acc;
    }
}

extern "C" void kernel_launch(void* const* d_in, const int* in_sizes, int n_in,
                              void* d_out, int out_size, void* d_ws, size_t ws_size,
                              hipStream_t stream)
{
    const float* x    = (const float*)d_in[0];
    const float* k1_w = (const float*)d_in[1];
    const float* k1_b = (const float*)d_in[2];
    const float* dw_w = (const float*)d_in[3];
    const float* dw_b = (const float*)d_in[4];
    const float* k3_w = (const float*)d_in[5];
    const float* k3_b = (const float*)d_in[6];
    const float* v_w  = (const float*)d_in[7];
    const float* v_b  = (const float*)d_in[8];
    const float* o_w  = (const float*)d_in[9];
    const float* o_b  = (const float*)d_in[10];
    float* out = (float*)d_out;

    // workspace: k1 (16 MiB) | v (16 MiB) | y (16 MiB)
    float* k1 = (float*)d_ws;
    float* v  = k1 + (size_t)Bc * CKc * HWc;
    float* y  = v  + (size_t)Bc * CVc * HWc;

    const int npx = Bc * HWc;                   // 131072 pixels

    ns_k1v<<<dim3(npx / TPX), dim3(256), 0, stream>>>(x, k1_w, k1_b, v_w, v_b, k1, v);
    ns_wts_y<<<dim3(npx / 256), dim3(256), 0, stream>>>(k1, v, dw_w, dw_b, k3_w, k3_b, y);
    ns_out<<<dim3(npx / TPX), dim3(256), 0, stream>>>(x, y, o_w, o_b, out);
}

// Round 3
// 159.433 us; speedup vs baseline: 3.5440x; 3.1734x over previous
//
#include <hip/hip_runtime.h>
#include <cmath>

namespace {
constexpr int Cc = 256, CKc = 32, CVc = 32, KKc = 9;
constexpr int Bc = 8, Hc = 128, Wc = 128, HWc = Hc * Wc;
}

// ---- Kernel 1: k1 = relu(W_k1 x + b), v = W_v x + b ----
// 256 thr = 4 waves; wave og: 0,1 -> k1 rows [0:16),[16:32); 2,3 -> v rows.
// Each thread: 2 pixels, 16 output rows. Weights staged per-64ch-chunk in LDS.
__global__ __launch_bounds__(256) void ns_k1v(
    const float* __restrict__ x,
    const float* __restrict__ k1_w, const float* __restrict__ k1_b,
    const float* __restrict__ v_w,  const float* __restrict__ v_b,
    float* __restrict__ k1, float* __restrict__ v)
{
    __shared__ float ws_t[64][68];              // [ch][oc], pad->no write conflicts, rows 16B-aligned
    const int tid = threadIdx.x;
    const int q  = tid & 63;                    // lane = pixel pair index
    const int og = __builtin_amdgcn_readfirstlane(tid >> 6);
    const int og16 = og * 16;

    const int flat0 = blockIdx.x * 128;         // 128 px per block
    const int b  = flat0 / HWc;
    const int pb = flat0 - b * HWc;

    const float* xg0 = x + (size_t)b * Cc * HWc + pb + q * 2;

    // staging roles
    const int soc = tid >> 2;                   // 0..63 output row
    const int sci = tid & 3;

    float2 acc[16];
#pragma unroll
    for (int o = 0; o < 16; ++o) acc[o] = make_float2(0.f, 0.f);

    for (int c0 = 0; c0 < Cc; c0 += 64) {
        __syncthreads();
        // stage transposed weights: ws_t[ch][oc] = W[oc][c0+ch] (k rows 0..31, v rows 32..63)
#pragma unroll
        for (int rep = 0; rep < 4; ++rep) {
            const int ch0 = rep * 16 + sci * 4;
            const float* src = (soc < 32) ? (k1_w + soc * Cc + c0 + ch0)
                                          : (v_w + (soc - 32) * Cc + c0 + ch0);
            const float4 val = *(const float4*)src;
            ws_t[ch0 + 0][soc] = val.x;
            ws_t[ch0 + 1][soc] = val.y;
            ws_t[ch0 + 2][soc] = val.z;
            ws_t[ch0 + 3][soc] = val.w;
        }
        __syncthreads();

        const float* xg = xg0 + (size_t)c0 * HWc;
#pragma unroll 4
        for (int ch = 0; ch < 64; ++ch) {
            const float2 xv = *(const float2*)(xg + (size_t)ch * HWc);
            float wv[16];
            *(float4*)&wv[0]  = *(const float4*)&ws_t[ch][og16 + 0];
            *(float4*)&wv[4]  = *(const float4*)&ws_t[ch][og16 + 4];
            *(float4*)&wv[8]  = *(const float4*)&ws_t[ch][og16 + 8];
            *(float4*)&wv[12] = *(const float4*)&ws_t[ch][og16 + 12];
#pragma unroll
            for (int o = 0; o < 16; ++o) {
                acc[o].x = fmaf(wv[o], xv.x, acc[o].x);
                acc[o].y = fmaf(wv[o], xv.y, acc[o].y);
            }
        }
    }

    const bool is_k = og < 2;
    const float* bsrc = is_k ? (k1_b + og16) : (v_b + (og16 - 32));
    float* dst = is_k ? (k1 + ((size_t)b * CKc + og16) * HWc + pb + q * 2)
                      : (v  + ((size_t)b * CVc + (og16 - 32)) * HWc + pb + q * 2);
#pragma unroll
    for (int o = 0; o < 16; ++o) {
        const float bi = bsrc[o];
        float2 r = make_float2(acc[o].x + bi, acc[o].y + bi);
        if (is_k) { r.x = fmaxf(r.x, 0.f); r.y = fmaxf(r.y, 0.f); }
        *(float2*)(dst + (size_t)o * HWc) = r;
    }
}

// -- Kernel 2: depthwise 3x3 + 1x1 CK->9 + softmax + unfold-aggregate -> y --
__global__ __launch_bounds__(256) void ns_wts_y(
    const float* __restrict__ k1,
    const float* __restrict__ v,
    const float* __restrict__ dw_w, const float* __restrict__ dw_b,
    const float* __restrict__ k3_w, const float* __restrict__ k3_b,
    float* __restrict__ y)
{
    __shared__ float dwt[KKc][CKc];    // transposed depthwise weights
    __shared__ float k3s[KKc][CKc];    // as-is
    __shared__ float dwbs[CKc];
    __shared__ float k3bs[KKc];
    const int tid = threadIdx.x;
    if (tid < 288) {
        const int ck = tid / KKc, kk = tid - ck * KKc;
        dwt[kk][ck] = dw_w[tid];
        ((float*)k3s)[tid] = k3_w[tid];
    }
    if (tid < CKc) dwbs[tid] = dw_b[tid];
    if (tid < KKc) k3bs[tid] = k3_b[tid];
    __syncthreads();

    const int gid = blockIdx.x * 256 + tid;
    const int b = gid / HWc;
    const int p = gid - b * HWc;
    const int h = p / Wc;
    const int w = p - h * Wc;
    const float* k1b = k1 + (size_t)b * CKc * HWc;

    float t[CKc];
#pragma unroll
    for (int ck = 0; ck < CKc; ++ck) t[ck] = dwbs[ck];

#pragma unroll
    for (int i = 0; i < 3; ++i) {
        const int hh = h + i - 1;
        if (hh < 0 || hh >= Hc) continue;
#pragma unroll
        for (int j = 0; j < 3; ++j) {
            const int ww = w + j - 1;
            if (ww < 0 || ww >= Wc) continue;
            const int off = hh * Wc + ww;
            const int ij = i * 3 + j;
#pragma unroll
            for (int ck = 0; ck < CKc; ++ck)
                t[ck] = fmaf(k1b[(size_t)ck * HWc + off], dwt[ij][ck], t[ck]);
        }
    }

    float logit[KKc];
#pragma unroll
    for (int kk = 0; kk < KKc; ++kk) {
        float a = k3bs[kk];
#pragma unroll
        for (int ck = 0; ck < CKc; ++ck)
            a = fmaf(k3s[kk][ck], t[ck], a);
        logit[kk] = a;
    }

    float m = logit[0];
#pragma unroll
    for (int kk = 1; kk < KKc; ++kk) m = fmaxf(m, logit[kk]);
    float s = 0.f;
#pragma unroll
    for (int kk = 0; kk < KKc; ++kk) { logit[kk] = expf(logit[kk] - m); s += logit[kk]; }
    const float inv = 1.f / s;
#pragma unroll
    for (int kk = 0; kk < KKc; ++kk) logit[kk] *= inv;

    float yv[CVc];
#pragma unroll
    for (int cv = 0; cv < CVc; ++cv) yv[cv] = 0.f;

    const float* vb = v + (size_t)b * CVc * HWc;
#pragma unroll
    for (int i = 0; i < 3; ++i) {
        const int hh = h + i - 1;
        if (hh < 0 || hh >= Hc) continue;
#pragma unroll
        for (int j = 0; j < 3; ++j) {
            const int ww = w + j - 1;
            if (ww < 0 || ww >= Wc) continue;
            const int off = hh * Wc + ww;
            const float wv = logit[i * 3 + j];
#pragma unroll
            for (int cv = 0; cv < CVc; ++cv)
                yv[cv] = fmaf(wv, vb[(size_t)cv * HWc + off], yv[cv]);
        }
    }

    float* yb = y + (size_t)b * CVc * HWc + p;
#pragma unroll
    for (int cv = 0; cv < CVc; ++cv) yb[(size_t)cv * HWc] = yv[cv];
}

// ---- Kernel 3: out = x + W_o y + b_o.  o_w staged once in LDS (32 KiB). ----
__global__ __launch_bounds__(256) void ns_out(
    const float* __restrict__ x,
    const float* __restrict__ y,
    const float* __restrict__ o_w, const float* __restrict__ o_b,
    float* __restrict__ out)
{
    __shared__ float ws[Cc * CVc];              // 32 KiB, same layout as o_w
    const int tid = threadIdx.x;
#pragma unroll
    for (int r = 0; r < 8; ++r) {
        const int idx = (r * 256 + tid) * 4;
        *(float4*)&ws[idx] = *(const float4*)&o_w[idx];
    }
    __syncthreads();

    const int q  = tid & 63;
    const int og = __builtin_amdgcn_readfirstlane(tid >> 6);   // 64 out-ch per og

    const int flat0 = blockIdx.x * 128;
    const int b  = flat0 / HWc;
    const int pb = flat0 - b * HWc;
    const int px = pb + q * 2;

    const float* yb = y + (size_t)b * CVc * HWc + px;
    float2 yv[CVc];
#pragma unroll
    for (int cv = 0; cv < CVc; ++cv) yv[cv] = *(const float2*)(yb + (size_t)cv * HWc);

    const float* xb = x + ((size_t)b * Cc + og * 64) * HWc + px;
    float* ob = out + ((size_t)b * Cc + og * 64) * HWc + px;
    const float* brow = o_b + og * 64;

#pragma unroll 4
    for (int o = 0; o < 64; ++o) {
        float wv[CVc];
#pragma unroll
        for (int r = 0; r < 8; ++r)
            *(float4*)&wv[r * 4] = *(const float4*)&ws[(og * 64 + o) * CVc + r * 4];
        const float bi = brow[o];
        const float2 xv = *(const float2*)(xb + (size_t)o * HWc);
        float ax = bi + xv.x, ay = bi + xv.y;
#pragma unroll
        for (int cv = 0; cv < CVc; ++cv) {
            ax = fmaf(wv[cv], yv[cv].x, ax);
            ay = fmaf(wv[cv], yv[cv].y, ay);
        }
        *(float2*)(ob + (size_t)o * HWc) = make_float2(ax, ay);
    }
}

extern "C" void kernel_launch(void* const* d_in, const int* in_sizes, int n_in,
                              void* d_out, int out_size, void* d_ws, size_t ws_size,
                              hipStream_t stream)
{
    const float* x    = (const float*)d_in[0];
    const float* k1_w = (const float*)d_in[1];
    const float* k1_b = (const float*)d_in[2];
    const float* dw_w = (const float*)d_in[3];
    const float* dw_b = (const float*)d_in[4];
    const float* k3_w = (const float*)d_in[5];
    const float* k3_b = (const float*)d_in[6];
    const float* v_w  = (const float*)d_in[7];
    const float* v_b  = (const float*)d_in[8];
    const float* o_w  = (const float*)d_in[9];
    const float* o_b  = (const float*)d_in[10];
    float* out = (float*)d_out;

    // workspace: k1 (16 MiB) | v (16 MiB) | y (16 MiB)
    float* k1 = (float*)d_ws;
    float* v  = k1 + (size_t)Bc * CKc * HWc;
    float* y  = v  + (size_t)Bc * CVc * HWc;

    const int npx = Bc * HWc;                   // 131072

    ns_k1v <<<dim3(npx / 128), dim3(256), 0, stream>>>(x, k1_w, k1_b, v_w, v_b, k1, v);
    ns_wts_y<<<dim3(npx / 256), dim3(256), 0, stream>>>(k1, v, dw_w, dw_b, k3_w, k3_b, y);
    ns_out <<<dim3(npx / 128), dim3(256), 0, stream>>>(x, y, o_w, o_b, out);
}